// Round 1
// 215.834 us; speedup vs baseline: 1.2123x; 1.2123x over previous
//
#include <hip/hip_runtime.h>
#include <hip/hip_bf16.h>

// SelectiveSSM: B=1, L=2048, D_MODEL=512, D_INNER=1024, D_STATE=16, D_CONV=4
// ESTABLISHED: inputs fp32, d_out fp32, ws >= 17.05MB (R6 fp32 path ran).
// R16 (262us): 64-tile GEMMs, conv+transpose fused, 9 launches.
// R17: scan_kernel serial-chain removal. Counters showed scan (105us) is
// latency-bound (VALUBusy 27%, HBM 22%, occ 42% = structural max). The
// exp2->rcp->fmaf chain per k-step is replaced by an exclusive log-prefix
// P[k] kept in registers (reusing u2[]'s 32 regs): rcpA_k = min(exp2(-(O+P_k)),
// 1e10) and h_k = exp2(O+P_k)*S_k (clamped logs telescope exactly), so all
// transcendentals become independent across k; only a 4-cy fmaf chain remains.
// ws 16.27MB: xz 8MB@0 | buf1 4MB@8 | shared 4MB@12 (WinT 2MB -> xsT 4MB ->
// WoutT 1MB) | xpcT 270KB@16MB.

#define L_SEQ 2048
#define DM 512
#define DI 1024
#define DS 16
#define NXP 33
#define EPS 1e-10f
#define RCPEPS 1e10f
#define LOG2E 1.44269504088896340736f
#define LN2 0.69314718055994530942f
#define LOG2EPS -33.219280948873623478f  // log2(1e-10)

typedef __hip_bfloat16 bf16;
typedef __attribute__((ext_vector_type(8))) short bf16x8v;
typedef __attribute__((ext_vector_type(4))) float f32x4v;
typedef __attribute__((ext_vector_type(4))) unsigned int u32x4v;

__device__ __forceinline__ float ldf(const float* p) { return *p; }
__device__ __forceinline__ float ldf(const bf16* p) { return __bfloat162float(*p); }

__device__ __forceinline__ void st1(float* p, float v) { *p = v; }
__device__ __forceinline__ void st1(bf16* p, float v) { *p = __float2bfloat16(v); }

__device__ __forceinline__ float fexp2(float x) { return __builtin_amdgcn_exp2f(x); }
__device__ __forceinline__ float frcp(float x) { return __builtin_amdgcn_rcpf(x); }

__device__ __forceinline__ void load8(const float* p, float* v) {
  float4 a = *(const float4*)p;
  float4 b = *(const float4*)(p + 4);
  v[0] = a.x; v[1] = a.y; v[2] = a.z; v[3] = a.w;
  v[4] = b.x; v[5] = b.y; v[6] = b.z; v[7] = b.w;
}
__device__ __forceinline__ void load8(const bf16* p, float* v) {
  bf16 t[8];
  *(uint4*)t = *(const uint4*)p;
#pragma unroll
  for (int j = 0; j < 8; ++j) v[j] = __bfloat162float(t[j]);
}

// W[R][C] fp32 -> WT[C][R] bf16, 32x32 LDS tiles. grid (C/32, R/32), 256 thr.
__global__ __launch_bounds__(256)
void transpose_cast_kernel(const float* __restrict__ W, bf16* __restrict__ WT,
                           int R, int C) {
  __shared__ float tile[32][33];
  int c0 = blockIdx.x * 32, r0 = blockIdx.y * 32;
  int tx = threadIdx.x & 31, ty = threadIdx.x >> 5;
#pragma unroll
  for (int i = 0; i < 4; ++i) {
    int rr = ty + i * 8;
    tile[rr][tx] = W[(size_t)(r0 + rr) * C + c0 + tx];
  }
  __syncthreads();
#pragma unroll
  for (int i = 0; i < 4; ++i) {
    int cc = ty + i * 8;
    WT[(size_t)(c0 + cc) * R + r0 + tx] = __float2bfloat16(tile[tx][cc]);
  }
}

// ---------- 64-tile MFMA GEMM: C[M][N] = A[M][K] @ BT[N][K]^T ----------
// A: fp32 (cast-on-stage, contiguous) or bf16. BT: bf16 rows of length K.
template <typename TA, typename TC>
__global__ __launch_bounds__(256)
void gemm_bt64(const TA* __restrict__ A, const bf16* __restrict__ BT,
               TC* __restrict__ C, int M, int N, int K, int lda, int ldc) {
  __shared__ __align__(16) bf16 As[64 * 40];
  __shared__ __align__(16) bf16 Bs[64 * 40];
  const int tid = threadIdx.x;
  const int wave = tid >> 6, lane = tid & 63;
  const int q = lane >> 4, r = lane & 15;
  const int row0 = blockIdx.y * 64, col0 = blockIdx.x * 64;
  const int srow = tid >> 2, sseg = tid & 3;
  f32x4v acc[4] = {};
  for (int k0 = 0; k0 < K; k0 += 32) {
    {
      float v[8];
      load8(A + (size_t)(row0 + srow) * lda + k0 + sseg * 8, v);
      bf16* dst = &As[srow * 40 + sseg * 8];
#pragma unroll
      for (int j = 0; j < 8; ++j) dst[j] = __float2bfloat16(v[j]);
    }
    *(uint4*)&Bs[srow * 40 + sseg * 8] =
        *(const uint4*)(BT + (size_t)(col0 + srow) * K + k0 + sseg * 8);
    __syncthreads();
    bf16x8v a = *(const bf16x8v*)&As[(wave * 16 + r) * 40 + q * 8];
#pragma unroll
    for (int j = 0; j < 4; ++j) {
      bf16x8v b = *(const bf16x8v*)&Bs[(j * 16 + r) * 40 + q * 8];
      acc[j] = __builtin_amdgcn_mfma_f32_16x16x32_bf16(a, b, acc[j], 0, 0, 0);
    }
    __syncthreads();
  }
#pragma unroll
  for (int j = 0; j < 4; ++j)
#pragma unroll
    for (int reg = 0; reg < 4; ++reg) {
      int m = row0 + wave * 16 + q * 4 + reg;
      int n = col0 + j * 16 + r;
      st1(C + (size_t)m * ldc + n, acc[j][reg]);
    }
}

// bf16 staging variant of A (direct uint4 copy, no cvt)
template <>
__global__ __launch_bounds__(256)
void gemm_bt64<bf16, float>(const bf16* __restrict__ A, const bf16* __restrict__ BT,
                            float* __restrict__ C, int M, int N, int K,
                            int lda, int ldc) {
  __shared__ __align__(16) bf16 As[64 * 40];
  __shared__ __align__(16) bf16 Bs[64 * 40];
  const int tid = threadIdx.x;
  const int wave = tid >> 6, lane = tid & 63;
  const int q = lane >> 4, r = lane & 15;
  const int row0 = blockIdx.y * 64, col0 = blockIdx.x * 64;
  const int srow = tid >> 2, sseg = tid & 3;
  f32x4v acc[4] = {};
  for (int k0 = 0; k0 < K; k0 += 32) {
    *(uint4*)&As[srow * 40 + sseg * 8] =
        *(const uint4*)(A + (size_t)(row0 + srow) * lda + k0 + sseg * 8);
    *(uint4*)&Bs[srow * 40 + sseg * 8] =
        *(const uint4*)(BT + (size_t)(col0 + srow) * K + k0 + sseg * 8);
    __syncthreads();
    bf16x8v a = *(const bf16x8v*)&As[(wave * 16 + r) * 40 + q * 8];
#pragma unroll
    for (int j = 0; j < 4; ++j) {
      bf16x8v b = *(const bf16x8v*)&Bs[(j * 16 + r) * 40 + q * 8];
      acc[j] = __builtin_amdgcn_mfma_f32_16x16x32_bf16(a, b, acc[j], 0, 0, 0);
    }
    __syncthreads();
  }
#pragma unroll
  for (int j = 0; j < 4; ++j)
#pragma unroll
    for (int reg = 0; reg < 4; ++reg) {
      int m = row0 + wave * 16 + q * 4 + reg;
      int n = col0 + j * 16 + r;
      st1(C + (size_t)m * ldc + n, acc[j][reg]);
    }
}

// ---------- xproj GEMM (R15-proven): xpcT[j][l] = (xs @ W_xproj)[l][j] ----
__global__ __launch_bounds__(256)
void gemm_xproj(const bf16* __restrict__ A, const float* __restrict__ Wx,
                float* __restrict__ xpcT) {
  __shared__ __align__(16) bf16 As[64 * 40];
  __shared__ __align__(16) bf16 Bs[64 * 40];
  const int tid = threadIdx.x;
  const int wave = tid >> 6, lane = tid & 63;
  const int q = lane >> 4, r = lane & 15;
  const int row0 = blockIdx.y * 64;
  const int srow = tid >> 2, sseg = tid & 3;
  f32x4v acc[4] = {};
  for (int k0 = 0; k0 < DI; k0 += 32) {
    *(uint4*)&As[srow * 40 + sseg * 8] =
        *(const uint4*)(A + (size_t)(row0 + srow) * DI + k0 + sseg * 8);
    int k = tid >> 3, n0 = (tid & 7) * 8;
#pragma unroll
    for (int j = 0; j < 8; ++j) {
      int n = n0 + j;
      float v = (n < NXP) ? Wx[(size_t)(k0 + k) * NXP + n] : 0.f;
      Bs[n * 40 + k] = __float2bfloat16(v);
    }
    __syncthreads();
    bf16x8v a = *(const bf16x8v*)&As[(wave * 16 + r) * 40 + q * 8];
#pragma unroll
    for (int j = 0; j < 4; ++j) {
      bf16x8v b = *(const bf16x8v*)&Bs[(j * 16 + r) * 40 + q * 8];
      acc[j] = __builtin_amdgcn_mfma_f32_16x16x32_bf16(a, b, acc[j], 0, 0, 0);
    }
    __syncthreads();
  }
#pragma unroll
  for (int j = 0; j < 4; ++j)
#pragma unroll
    for (int reg = 0; reg < 4; ++reg) {
      int m = row0 + wave * 16 + q * 4 + reg;
      int n = j * 16 + r;
      if (n < NXP) xpcT[(size_t)n * L_SEQ + m] = acc[j][reg];
    }
}

// ---------- conv + silu, dual-layout output ----------
// Reads xz x-half (ld 2048), writes xs to buf1[l][d] and xsT[d][l].
// grid (DI/64, L/64), 256 threads. Causal width-4 conv along l.
__global__ __launch_bounds__(256)
void conv_silu_dual(const bf16* __restrict__ xz, const float* __restrict__ conv_w,
                    const float* __restrict__ conv_b, bf16* __restrict__ xs,
                    bf16* __restrict__ xsT) {
  __shared__ bf16 tile[67][72];   // rows l0-3 .. l0+63
  __shared__ bf16 sout[64][72];   // [d][l]
  const int tid = threadIdx.x;
  const int d0 = blockIdx.x * 64, l0 = blockIdx.y * 64;
  // stage 67 rows x 64 cols
  for (int slot = tid; slot < 67 * 8; slot += 256) {
    int rr = slot >> 3, seg = slot & 7;
    int l = l0 - 3 + rr;
    uint4 v = {0, 0, 0, 0};
    if (l >= 0) v = *(const uint4*)(xz + (size_t)l * (2 * DI) + d0 + seg * 8);
    *(uint4*)&tile[rr][seg * 8] = v;
  }
  __syncthreads();
  // compute: thread -> 2 rows x 8 cols
  {
    int lr = tid >> 3, c0t = (tid & 7) * 8;
#pragma unroll
    for (int half = 0; half < 2; ++half) {
      int lrow = lr + half * 32;
      bf16 o[8];
#pragma unroll
      for (int j = 0; j < 8; ++j) {
        int c = c0t + j;
        float acc = conv_b[d0 + c];
#pragma unroll
        for (int k = 0; k < 4; ++k)
          acc = fmaf(__bfloat162float(tile[lrow + k][c]), conv_w[(d0 + c) * 4 + k], acc);
        float v = acc / (1.f + __expf(-acc));
        o[j] = __float2bfloat16(v);
        sout[c][lrow] = o[j];
      }
      *(uint4*)(xs + (size_t)(l0 + lrow) * DI + d0 + c0t) = *(uint4*)o;
    }
  }
  __syncthreads();
  for (int slot = tid; slot < 64 * 8; slot += 256) {
    int dd = slot >> 3, seg = slot & 7;
    *(uint4*)(xsT + (size_t)(d0 + dd) * L_SEQ + l0 + seg * 8) =
        *(uint4*)&sout[dd][seg * 8];
  }
}

// ys[l][d] = yT[d][l] * silu(z[l][d]); z has leading dim ldz.
__global__ __launch_bounds__(256)
void gate_transpose_kernel(const bf16* __restrict__ yT, const bf16* __restrict__ zbuf,
                           int ldz, bf16* __restrict__ ys) {
  __shared__ bf16 tile[64][72];
  int d0 = blockIdx.y * 64, l0 = blockIdx.x * 64;
#pragma unroll
  for (int it = 0; it < 2; ++it) {
    int slot = threadIdx.x + it * 256;
    int dd = slot >> 3, seg = slot & 7;
    *(uint4*)&tile[dd][seg * 8] = *(const uint4*)(yT + (size_t)(d0 + dd) * L_SEQ + l0 + seg * 8);
  }
  __syncthreads();
#pragma unroll
  for (int it = 0; it < 2; ++it) {
    int slot = threadIdx.x + it * 256;
    int ll = slot >> 3, seg = slot & 7;
    bf16 zt[8];
    *(uint4*)zt = *(const uint4*)(zbuf + (size_t)(l0 + ll) * ldz + d0 + seg * 8);
    bf16 o[8];
#pragma unroll
    for (int j = 0; j < 8; ++j) {
      float yv = __bfloat162float(tile[seg * 8 + j][ll]);
      float zv = __bfloat162float(zt[j]);
      o[j] = __float2bfloat16(yv * zv * frcp(1.f + fexp2(-zv * LOG2E)));
    }
    *(uint4*)(ys + (size_t)(l0 + ll) * DI + d0 + seg * 8) = *(uint4*)o;
  }
}

// ---------- chunk-parallel scan ----------
// R17: exclusive log-prefix P[k] in registers; per-k scale factors computed
// directly as exp2(+/-(O+P[k])) -> no exp2/rcp serial chain; only the S/Vl
// fmaf accumulation (4cy) is serial across k.
#define LC 512
#define NW 16
#define SPW 32
#define PSX 513
#define LCP 516

__global__ __launch_bounds__(1024)
void scan_kernel(bf16* __restrict__ xsT, const float* __restrict__ xpcT,
                 const float* __restrict__ dt_w, const float* __restrict__ dt_b,
                 const float* __restrict__ A_log, const float* __restrict__ Dvec) {
  __shared__ float sxpT[NXP * PSX];
  __shared__ float sdt[4 * LCP], sg[4 * LCP], sxs[4 * LCP];
  __shared__ float sys[4 * LCP];
  __shared__ float Wtot[NW][64], Vtot[NW][64];
  const int tid = threadIdx.x;
  const int wave = tid >> 6, lane = tid & 63;
  const int s = lane & 15, dl = lane >> 4;
  const int d0 = blockIdx.x * 4;
  const int base = wave * SPW;
  const float As2 = -expf(A_log[s]) * LOG2E;
  const float Dd = Dvec[d0 + dl];
  float dtw[4], dtb[4];
#pragma unroll
  for (int c = 0; c < 4; ++c) {
    dtw[c] = dt_w[d0 + c];
    dtb[c] = dt_b[d0 + c];
  }
  float cs2_carry = 0.f, S_carry = 0.f;
  for (int l0 = 0; l0 < L_SEQ; l0 += LC) {
    for (int idx = tid; idx < NXP * LC; idx += 1024) {
      int j = idx >> 9, l = idx & (LC - 1);
      sxpT[j * PSX + l] = xpcT[(size_t)j * L_SEQ + l0 + l];
    }
    for (int slot = tid; slot < 4 * (LC / 8); slot += 1024) {
      int c = slot >> 6, seg = slot & 63;
      bf16 tmp[8];
      *(uint4*)tmp = *(const uint4*)(xsT + (size_t)(d0 + c) * L_SEQ + l0 + seg * 8);
#pragma unroll
      for (int j = 0; j < 8; ++j) sxs[c * LCP + seg * 8 + j] = __bfloat162float(tmp[j]);
    }
    __syncthreads();
    for (int i = tid; i < LC; i += 1024) {
      float x0 = sxpT[i];
#pragma unroll
      for (int c = 0; c < 4; ++c) {
        float a = fmaf(x0, dtw[c], dtb[c]);
        float dt = __log2f(1.f + fexp2(a * LOG2E)) * LN2;
        sdt[c * LCP + i] = dt;
        sg[c * LCP + i] = dt * sxs[c * LCP + i];
      }
    }
    __syncthreads();
    // Pass C: exclusive prefix of clamped log2 A_bar (per wave's 32 positions)
    float P[SPW];
    float Wl = 0.f;
#pragma unroll
    for (int k = 0; k < SPW; ++k) {
      float u = sdt[dl * LCP + base + k] * As2;
      P[k] = Wl;                       // exclusive prefix
      Wl += fmaxf(u, LOG2EPS);
    }
    Wtot[wave][lane] = Wl;
    __syncthreads();
    float O = cs2_carry, Wall = 0.f;
    for (int w = 0; w < NW; ++w) {
      float t = Wtot[w][lane];
      if (w < wave) O += t;
      Wall += t;
    }
    // Pass E: V partial sum. rcpA_k = rcp(max(exp2(O+P_k),EPS)) = min(exp2(-(O+P_k)),1e10)
    float Vl = 0.f;
#pragma unroll
    for (int k = 0; k < SPW; ++k) {
      float rcpA = fminf(fexp2(-(O + P[k])), RCPEPS);
      float gb = sg[dl * LCP + base + k] * sxpT[(1 + s) * PSX + base + k];
      Vl = fmaf(gb, rcpA, Vl);
    }
    Vtot[wave][lane] = Vl;
    __syncthreads();
    float SO = S_carry, Vall = 0.f;
    for (int w = 0; w < NW; ++w) {
      float t = Vtot[w][lane];
      if (w < wave) SO += t;
      Vall += t;
    }
    // Pass G: h_k = acum_{k-1} * S_k  (acum_k/max(A_bar_k,EPS) telescopes exactly)
    float S = SO;
#pragma unroll
    for (int k = 0; k < SPW; ++k) {
      float xk = O + P[k];
      float rcpA = fminf(fexp2(-xk), RCPEPS);
      float aprev = fexp2(xk);
      float gb = sg[dl * LCP + base + k] * sxpT[(1 + s) * PSX + base + k];
      S = fmaf(gb, rcpA, S);
      float h = aprev * S;
      float contrib = sxpT[(17 + s) * PSX + base + k] * h;
      contrib += __shfl_xor(contrib, 8);
      contrib += __shfl_xor(contrib, 4);
      contrib += __shfl_xor(contrib, 2);
      contrib += __shfl_xor(contrib, 1);
      if (s == 0)
        sys[dl * LCP + base + k] = contrib + Dd * sxs[dl * LCP + base + k];
    }
    cs2_carry += Wall;
    S_carry += Vall;
    __syncthreads();
    for (int slot = tid; slot < 4 * (LC / 8); slot += 1024) {
      int c = slot >> 6, seg = slot & 63;
      bf16 tmp[8];
#pragma unroll
      for (int j = 0; j < 8; ++j) tmp[j] = __float2bfloat16(sys[c * LCP + seg * 8 + j]);
      u32x4v vv;
      vv.x = ((unsigned int*)tmp)[0]; vv.y = ((unsigned int*)tmp)[1];
      vv.z = ((unsigned int*)tmp)[2]; vv.w = ((unsigned int*)tmp)[3];
      __builtin_nontemporal_store(vv,
          (u32x4v*)(xsT + (size_t)(d0 + c) * L_SEQ + l0 + seg * 8));
    }
    __syncthreads();
  }
}

extern "C" void kernel_launch(void* const* d_in, const int* in_sizes, int n_in,
                              void* d_out, int out_size, void* d_ws, size_t ws_size,
                              hipStream_t stream) {
  const float* x       = (const float*)d_in[0];
  const float* W_in    = (const float*)d_in[1];
  const float* conv_w  = (const float*)d_in[2];
  const float* conv_b  = (const float*)d_in[3];
  const float* W_xproj = (const float*)d_in[4];
  const float* dt_w    = (const float*)d_in[5];
  const float* dt_b    = (const float*)d_in[6];
  const float* A_log   = (const float*)d_in[7];
  const float* Dvec    = (const float*)d_in[8];
  const float* W_out   = (const float*)d_in[9];
  float* out = (float*)d_out;

  char* ws = (char*)d_ws;
  const size_t MB = 1024 * 1024;
  bf16* xz    = (bf16*)(ws);             // [2048][2048]
  bf16* buf1  = (bf16*)(ws + 8 * MB);    // [2048][1024] xs, later gated ys
  bf16* WinT  = (bf16*)(ws + 12 * MB);   // [2048][512] (dead after gemm1)
  bf16* xsT   = (bf16*)(ws + 12 * MB);   // [1024][2048] overlays WinT
  bf16* WoutT = (bf16*)(ws + 12 * MB);   // [512][1024] overlays dead xsT (late)
  float* xpcT = (float*)(ws + 16 * MB);  // [33][2048]

  // 1) WinT = W_in^T bf16
  transpose_cast_kernel<<<dim3(2 * DI / 32, DM / 32), 256, 0, stream>>>(
      W_in, WinT, DM, 2 * DI);
  // 2) xz = x @ W_in  (full N=2048; A fp32 cast-on-stage)
  gemm_bt64<float, bf16><<<dim3(2 * DI / 64, L_SEQ / 64), 256, 0, stream>>>(
      x, WinT, xz, L_SEQ, 2 * DI, DM, DM, 2 * DI);
  // 3) conv + silu -> buf1[l][d] AND xsT[d][l]  (WinT dead)
  conv_silu_dual<<<dim3(DI / 64, L_SEQ / 64), 256, 0, stream>>>(
      xz, conv_w, conv_b, buf1, xsT);
  // 4) xpcT = (xs @ W_xproj)^T
  gemm_xproj<<<dim3(1, L_SEQ / 64), 256, 0, stream>>>(buf1, W_xproj, xpcT);
  // 5) scan: un-gated yT in place over xsT
  scan_kernel<<<DI / 4, 1024, 0, stream>>>(xsT, xpcT, dt_w, dt_b, A_log, Dvec);
  // 6) gate + transpose: ys[l][d] = yT * silu(z), z = xz cols 1024.. (ld 2048)
  gate_transpose_kernel<<<dim3(L_SEQ / 64, DI / 64), 256, 0, stream>>>(
      xsT, xz + DI, 2 * DI, buf1);
  // 7) WoutT = W_out^T bf16 (xsT dead now)
  transpose_cast_kernel<<<dim3(DM / 32, DI / 32), 256, 0, stream>>>(
      W_out, WoutT, DI, DM);
  // 8) out = ys @ W_out
  gemm_bt64<bf16, float><<<dim3(DM / 64, L_SEQ / 64), 256, 0, stream>>>(
      buf1, WoutT, out, L_SEQ, DM, DI, DI, DM);
}